// Round 1
// baseline (539.613 us; speedup 1.0000x reference)
//
#include <hip/hip_runtime.h>

#define NEG_ATT 0.2f   // GATConv attention leaky_relu slope
#define NEG_ACT 0.01f  // inter-layer leaky_relu slope

__device__ __forceinline__ float lrelu(float x, float sl) { return x > 0.0f ? x : x * sl; }

// ---------------- histogram (edge dst counts / batch counts) ----------------
__global__ void hist_kernel(const int* __restrict__ idx, int* __restrict__ count, int n) {
  int i = blockIdx.x * blockDim.x + threadIdx.x;
  if (i < n) atomicAdd(&count[idx[i]], 1);
}

// ---------------- exclusive scan (3-phase, n <= 256*256) ----------------
__global__ void scan_block_kernel(int* __restrict__ data, int* __restrict__ partials, int n) {
  __shared__ int tmp[256];
  int gid = blockIdx.x * 256 + threadIdx.x;
  int v = (gid < n) ? data[gid] : 0;
  tmp[threadIdx.x] = v;
  __syncthreads();
  for (int off = 1; off < 256; off <<= 1) {
    int t = (threadIdx.x >= (unsigned)off) ? tmp[threadIdx.x - off] : 0;
    __syncthreads();
    tmp[threadIdx.x] += t;
    __syncthreads();
  }
  if (gid < n) data[gid] = tmp[threadIdx.x] - v;  // block-local exclusive
  if (threadIdx.x == 255) partials[blockIdx.x] = tmp[255];
}

__global__ void scan_partials_kernel(int* __restrict__ partials, int nb) {
  __shared__ int tmp[256];
  int v = (threadIdx.x < (unsigned)nb) ? partials[threadIdx.x] : 0;
  tmp[threadIdx.x] = v;
  __syncthreads();
  for (int off = 1; off < 256; off <<= 1) {
    int t = (threadIdx.x >= (unsigned)off) ? tmp[threadIdx.x - off] : 0;
    __syncthreads();
    tmp[threadIdx.x] += t;
    __syncthreads();
  }
  if (threadIdx.x < (unsigned)nb) partials[threadIdx.x] = tmp[threadIdx.x] - v;
}

__global__ void scan_finalize_kernel(int* __restrict__ start, int* __restrict__ cursor,
                                     const int* __restrict__ partials, int n, int total) {
  int gid = blockIdx.x * 256 + threadIdx.x;
  if (gid < n) {
    int v = start[gid] + partials[gid >> 8];
    start[gid] = v;
    cursor[gid] = v;
  }
  if (gid == 0) start[n] = total;
}

// ---------------- counting-sort scatter: edges grouped by dst ----------------
__global__ void scatter_kernel(const int* __restrict__ src, const int* __restrict__ dst,
                               int* __restrict__ cursor, int* __restrict__ ssrc, int E) {
  int i = blockIdx.x * blockDim.x + threadIdx.x;
  if (i < E) {
    int p = atomicAdd(&cursor[dst[i]], 1);
    ssrc[p] = src[i];
  }
}

// ---------------- GEMM  h = X@W  with fused s=h@a_src, d=h@a_dst ----------------
// One wave per node row; W staged in LDS. DIN=128 always; FOUT in {128,64}.
template <int DIN, int FOUT>
__global__ __launch_bounds__(256) void gemm_sd_kernel(
    const float* __restrict__ X, const float* __restrict__ W,
    const float* __restrict__ asrc, const float* __restrict__ adst,
    float* __restrict__ Ho, float* __restrict__ So, float* __restrict__ Do, int N) {
  constexpr int CPL = FOUT / 64;  // cols per lane (2 or 1)
  __shared__ float Wl[DIN * FOUT];
  __shared__ float xr[4][DIN];
  int tid = threadIdx.x;
  for (int i = tid; i < DIN * FOUT; i += 256) Wl[i] = W[i];
  __syncthreads();
  int wave = tid >> 6, lane = tid & 63;
  float a0 = asrc[lane * CPL], b0 = adst[lane * CPL];
  float a1 = 0.0f, b1v = 0.0f;
  if constexpr (CPL == 2) { a1 = asrc[lane * 2 + 1]; b1v = adst[lane * 2 + 1]; }
  int base = blockIdx.x * 64 + wave * 16;
  for (int nn = 0; nn < 16; ++nn) {
    int n = base + nn;
    if (n >= N) break;  // wave-uniform
    // stage this node's x row into per-wave LDS (ds ops in-order per wave)
    float2 xv = *(const float2*)(X + (size_t)n * DIN + lane * 2);
    *(float2*)&xr[wave][lane * 2] = xv;
    float acc0 = 0.0f, acc1 = 0.0f;
#pragma unroll 16
    for (int k = 0; k < DIN; ++k) {
      float xs = xr[wave][k];  // LDS broadcast
      if constexpr (CPL == 2) {
        float2 wv = *(const float2*)&Wl[k * FOUT + lane * 2];
        acc0 = fmaf(xs, wv.x, acc0);
        acc1 = fmaf(xs, wv.y, acc1);
      } else {
        acc0 = fmaf(xs, Wl[k * FOUT + lane], acc0);
      }
    }
    if constexpr (CPL == 2)
      *(float2*)(Ho + (size_t)n * FOUT + lane * 2) = make_float2(acc0, acc1);
    else
      Ho[(size_t)n * FOUT + lane] = acc0;
    float ps = acc0 * a0, pd = acc0 * b0;
    if constexpr (CPL == 2) { ps = fmaf(acc1, a1, ps); pd = fmaf(acc1, b1v, pd); }
    for (int off = 32; off; off >>= 1) {
      ps += __shfl_xor(ps, off);
      pd += __shfl_xor(pd, off);
    }
    if (lane == 0) { So[n] = ps; Do[n] = pd; }
  }
}

// ---------------- per-dst-node attention aggregation (online softmax) ----------------
// One wave per node. Self-loop handled implicitly (not in sorted edge list).
template <int F, bool POOL>
__global__ __launch_bounds__(256) void agg_kernel(
    const float* __restrict__ Hm, const float* __restrict__ S, const float* __restrict__ Dv,
    const int* __restrict__ start, const int* __restrict__ ssrc,
    const float* __restrict__ bias, float* __restrict__ out,
    const int* __restrict__ batch, float* __restrict__ pool, int N) {
  constexpr int CPL = F / 64;
  int wave = threadIdx.x >> 6, lane = threadIdx.x & 63;
  int n = blockIdx.x * 4 + wave;
  if (n >= N) return;
  float dn = Dv[n];
  float m = lrelu(S[n] + dn, NEG_ATT);  // self-loop logit
  float sum = 1.0f;                     // exp(self - m) = 1
  float acc0, acc1 = 0.0f;
  if constexpr (CPL == 2) {
    float2 hv = *(const float2*)(Hm + (size_t)n * F + lane * 2);
    acc0 = hv.x; acc1 = hv.y;
  } else {
    acc0 = Hm[(size_t)n * F + lane];
  }
  int j1 = start[n + 1];
  for (int j = start[n]; j < j1; ++j) {
    int sj = ssrc[j];                      // uniform broadcast load
    float e = lrelu(S[sj] + dn, NEG_ATT);  // uniform
    float p;
    if (e > m) {  // wave-uniform branch
      float r = __expf(m - e);
      sum *= r; acc0 *= r;
      if constexpr (CPL == 2) acc1 *= r;
      m = e; p = 1.0f;
    } else {
      p = __expf(e - m);
    }
    sum += p;
    if constexpr (CPL == 2) {
      float2 hv = *(const float2*)(Hm + (size_t)sj * F + lane * 2);
      acc0 = fmaf(p, hv.x, acc0);
      acc1 = fmaf(p, hv.y, acc1);
    } else {
      acc0 = fmaf(p, Hm[(size_t)sj * F + lane], acc0);
    }
  }
  float inv = 1.0f / sum;
  if constexpr (!POOL) {
    if constexpr (CPL == 2) {
      float v0 = lrelu(fmaf(acc0, inv, 0.0f) + bias[lane * 2], NEG_ACT);
      float v1 = lrelu(fmaf(acc1, inv, 0.0f) + bias[lane * 2 + 1], NEG_ACT);
      *(float2*)(out + (size_t)n * F + lane * 2) = make_float2(v0, v1);
    } else {
      out[(size_t)n * F + lane] = lrelu(acc0 * inv + bias[lane], NEG_ACT);
    }
  } else {
    float v0 = acc0 * inv + bias[lane];
    atomicAdd(&pool[(size_t)batch[n] * F + lane], v0);
  }
}

// ---------------- mean-pool divide ----------------
__global__ void pool_div_kernel(const float* __restrict__ pool, const int* __restrict__ gcount,
                                float* __restrict__ out, int total, int O) {
  int i = blockIdx.x * blockDim.x + threadIdx.x;
  if (i < total) {
    int g = i / O;
    out[i] = pool[i] / fmaxf((float)gcount[g], 1.0f);
  }
}

extern "C" void kernel_launch(void* const* d_in, const int* in_sizes, int n_in,
                              void* d_out, int out_size, void* d_ws, size_t ws_size,
                              hipStream_t stream) {
  const float* x      = (const float*)d_in[0];
  const int*   ei     = (const int*)d_in[1];
  const int*   batch  = (const int*)d_in[2];
  const float* W1     = (const float*)d_in[4];
  const float* a_src1 = (const float*)d_in[5];
  const float* a_dst1 = (const float*)d_in[6];
  const float* b1     = (const float*)d_in[7];
  const float* W2     = (const float*)d_in[8];
  const float* a_src2 = (const float*)d_in[9];
  const float* a_dst2 = (const float*)d_in[10];
  const float* b2     = (const float*)d_in[11];
  float* out = (float*)d_out;

  const int D = 128, H = 128, O = 64;
  int N = in_sizes[0] / D;       // 50000
  int E = in_sizes[1] / 2;       // 800000
  int G = out_size / O;          // 256
  const int* src = ei;
  const int* dst = ei + E;

  // ---- workspace carve (aligned to 256B) ----
  char* w = (char*)d_ws;
  auto alloc = [&](size_t bytes) -> char* {
    char* p = w;
    w += (bytes + 255) & ~(size_t)255;
    return p;
  };
  float* h1     = (float*)alloc((size_t)N * H * 4);  // reused as h2 after layer-1 agg
  float* act1   = (float*)alloc((size_t)N * H * 4);
  int*   ssrc   = (int*)alloc((size_t)E * 4);
  int*   start  = (int*)alloc((size_t)(N + 1) * 4);  // counts -> exclusive prefix
  int*   cursor = (int*)alloc((size_t)N * 4);
  int*   parts  = (int*)alloc(4096 * 4);
  float* s1     = (float*)alloc((size_t)N * 4);
  float* d1     = (float*)alloc((size_t)N * 4);
  float* s2     = (float*)alloc((size_t)N * 4);
  float* d2     = (float*)alloc((size_t)N * 4);
  float* pool   = (float*)alloc((size_t)G * O * 4);
  int*   gcount = (int*)alloc((size_t)G * 4);
  float* h2 = h1;  // alias: h1 dead after layer-1 aggregation

  // ---- zero the accumulated buffers (ws is NOT re-poisoned between replays) ----
  hipMemsetAsync(start, 0, (size_t)(N + 1) * 4, stream);
  hipMemsetAsync(gcount, 0, (size_t)G * 4, stream);
  hipMemsetAsync(pool, 0, (size_t)G * O * 4, stream);

  // ---- counting sort of edges by dst (shared by both layers) ----
  hist_kernel<<<(E + 255) / 256, 256, 0, stream>>>(dst, start, E);
  hist_kernel<<<(N + 255) / 256, 256, 0, stream>>>(batch, gcount, N);
  int nb = (N + 255) / 256;
  scan_block_kernel<<<nb, 256, 0, stream>>>(start, parts, N);
  scan_partials_kernel<<<1, 256, 0, stream>>>(parts, nb);
  scan_finalize_kernel<<<nb, 256, 0, stream>>>(start, cursor, parts, N, E);
  scatter_kernel<<<(E + 255) / 256, 256, 0, stream>>>(src, dst, cursor, ssrc, E);

  // ---- layer 1 ----
  gemm_sd_kernel<128, 128><<<(N + 63) / 64, 256, 0, stream>>>(x, W1, a_src1, a_dst1, h1, s1, d1, N);
  agg_kernel<128, false><<<(N + 3) / 4, 256, 0, stream>>>(h1, s1, d1, start, ssrc, b1, act1,
                                                          nullptr, nullptr, N);
  // ---- layer 2 ----
  gemm_sd_kernel<128, 64><<<(N + 63) / 64, 256, 0, stream>>>(act1, W2, a_src2, a_dst2, h2, s2, d2, N);
  agg_kernel<64, true><<<(N + 3) / 4, 256, 0, stream>>>(h2, s2, d2, start, ssrc, b2, nullptr,
                                                        batch, pool, N);
  // ---- mean pool ----
  pool_div_kernel<<<(G * O + 255) / 256, 256, 0, stream>>>(pool, gcount, out, G * O, O);
}

// Round 2
// 402.943 us; speedup vs baseline: 1.3392x; 1.3392x over previous
//
#include <hip/hip_runtime.h>

#define NEG_ATT 0.2f   // GATConv attention leaky_relu slope
#define NEG_ACT 0.01f  // inter-layer leaky_relu slope

__device__ __forceinline__ float lrelu(float x, float sl) { return x > 0.0f ? x : x * sl; }

// ---------------- histogram (edge dst counts / batch counts) ----------------
__global__ void hist_kernel(const int* __restrict__ idx, int* __restrict__ count, int n) {
  int i = blockIdx.x * blockDim.x + threadIdx.x;
  if (i < n) atomicAdd(&count[idx[i]], 1);
}

// ---------------- exclusive scan (3-phase, n <= 256*256) ----------------
__global__ void scan_block_kernel(int* __restrict__ data, int* __restrict__ partials, int n) {
  __shared__ int tmp[256];
  int gid = blockIdx.x * 256 + threadIdx.x;
  int v = (gid < n) ? data[gid] : 0;
  tmp[threadIdx.x] = v;
  __syncthreads();
  for (int off = 1; off < 256; off <<= 1) {
    int t = (threadIdx.x >= (unsigned)off) ? tmp[threadIdx.x - off] : 0;
    __syncthreads();
    tmp[threadIdx.x] += t;
    __syncthreads();
  }
  if (gid < n) data[gid] = tmp[threadIdx.x] - v;  // block-local exclusive
  if (threadIdx.x == 255) partials[blockIdx.x] = tmp[255];
}

__global__ void scan_partials_kernel(int* __restrict__ partials, int nb) {
  __shared__ int tmp[256];
  int v = (threadIdx.x < (unsigned)nb) ? partials[threadIdx.x] : 0;
  tmp[threadIdx.x] = v;
  __syncthreads();
  for (int off = 1; off < 256; off <<= 1) {
    int t = (threadIdx.x >= (unsigned)off) ? tmp[threadIdx.x - off] : 0;
    __syncthreads();
    tmp[threadIdx.x] += t;
    __syncthreads();
  }
  if (threadIdx.x < (unsigned)nb) partials[threadIdx.x] = tmp[threadIdx.x] - v;
}

__global__ void scan_finalize_kernel(int* __restrict__ start, int* __restrict__ cursor,
                                     const int* __restrict__ partials, int n, int total) {
  int gid = blockIdx.x * 256 + threadIdx.x;
  if (gid < n) {
    int v = start[gid] + partials[gid >> 8];
    start[gid] = v;
    cursor[gid] = v;
  }
  if (gid == 0) start[n] = total;
}

// ---------------- counting-sort scatter: edges grouped by dst ----------------
__global__ void scatter_kernel(const int* __restrict__ src, const int* __restrict__ dst,
                               int* __restrict__ cursor, int* __restrict__ ssrc, int E) {
  int i = blockIdx.x * blockDim.x + threadIdx.x;
  if (i < E) {
    int p = atomicAdd(&cursor[dst[i]], 1);
    ssrc[p] = src[i];
  }
}

// ---------------- GEMM  h = X@W  with fused s=h@a_src, d=h@a_dst ----------------
// One wave per 16 node rows (2 groups of 8, register-blocked); W staged in LDS.
template <int DIN, int FOUT>
__global__ __launch_bounds__(256) void gemm_sd_kernel(
    const float* __restrict__ X, const float* __restrict__ W,
    const float* __restrict__ asrc, const float* __restrict__ adst,
    float* __restrict__ Ho, float* __restrict__ So, float* __restrict__ Do, int N) {
  constexpr int CPL = FOUT / 64;  // cols per lane (2 or 1)
  __shared__ float Wl[DIN * FOUT];
  __shared__ float xr[4][8][DIN];  // per-wave x-row stage (16 KB)
  int tid = threadIdx.x;
  for (int i = tid; i < DIN * FOUT; i += 256) Wl[i] = W[i];
  __syncthreads();
  int wave = tid >> 6, lane = tid & 63;
  float a0 = asrc[lane * CPL], b0 = adst[lane * CPL];
  float a1 = 0.0f, b1v = 0.0f;
  if constexpr (CPL == 2) { a1 = asrc[lane * 2 + 1]; b1v = adst[lane * 2 + 1]; }
  int base = blockIdx.x * 64 + wave * 16;
  for (int g = 0; g < 2; ++g) {
    int nb = base + g * 8;
    if (nb >= N) break;  // wave-uniform
    // stage 8 x rows into per-wave LDS (ds ops in-order within wave)
#pragma unroll
    for (int r = 0; r < 8; ++r) {
      int n = nb + r;
      float2 xv = make_float2(0.0f, 0.0f);
      if (n < N) xv = *(const float2*)(X + (size_t)n * DIN + lane * 2);
      *(float2*)&xr[wave][r][lane * 2] = xv;
    }
    float2 acc[8];
#pragma unroll
    for (int r = 0; r < 8; ++r) acc[r] = make_float2(0.0f, 0.0f);
    for (int k = 0; k < DIN; k += 4) {
      float4 xv[8];
#pragma unroll
      for (int r = 0; r < 8; ++r) xv[r] = *(const float4*)&xr[wave][r][k];  // b128 broadcast
#pragma unroll
      for (int kk = 0; kk < 4; ++kk) {
        if constexpr (CPL == 2) {
          float2 wv = *(const float2*)&Wl[(k + kk) * FOUT + lane * 2];
#pragma unroll
          for (int r = 0; r < 8; ++r) {
            float xs = (&xv[r].x)[kk];
            acc[r].x = fmaf(xs, wv.x, acc[r].x);
            acc[r].y = fmaf(xs, wv.y, acc[r].y);
          }
        } else {
          float wv = Wl[(k + kk) * FOUT + lane];
#pragma unroll
          for (int r = 0; r < 8; ++r) acc[r].x = fmaf((&xv[r].x)[kk], wv, acc[r].x);
        }
      }
    }
#pragma unroll
    for (int r = 0; r < 8; ++r) {
      int n = nb + r;
      if (n >= N) break;  // wave-uniform
      float acc0 = acc[r].x, acc1 = acc[r].y;
      if constexpr (CPL == 2)
        *(float2*)(Ho + (size_t)n * FOUT + lane * 2) = make_float2(acc0, acc1);
      else
        Ho[(size_t)n * FOUT + lane] = acc0;
      float ps = acc0 * a0, pd = acc0 * b0;
      if constexpr (CPL == 2) { ps = fmaf(acc1, a1, ps); pd = fmaf(acc1, b1v, pd); }
      for (int off = 32; off; off >>= 1) {
        ps += __shfl_xor(ps, off);
        pd += __shfl_xor(pd, off);
      }
      if (lane == 0) { So[n] = ps; Do[n] = pd; }
    }
  }
}

// ---------------- per-dst-node attention aggregation ----------------
// One wave per node. Two-phase per 64-edge chunk: lane-parallel logits
// (64 loads in flight) -> chunk-level online-softmax rescale -> broadcast
// accumulate with unrolled independent row gathers.
template <int F, bool POOL>
__global__ __launch_bounds__(256) void agg_kernel(
    const float* __restrict__ Hm, const float* __restrict__ S, const float* __restrict__ Dv,
    const int* __restrict__ start, const int* __restrict__ ssrc,
    const float* __restrict__ bias, float* __restrict__ out,
    const int* __restrict__ batch, float* __restrict__ pool, int N) {
  constexpr int CPL = F / 64;
  int wave = threadIdx.x >> 6, lane = threadIdx.x & 63;
  int n = blockIdx.x * 4 + wave;
  if (n >= N) return;
  float dn = Dv[n];
  float m = lrelu(S[n] + dn, NEG_ATT);  // self-loop logit
  float sum = 1.0f;                     // exp(self - m) = 1
  float acc0, acc1 = 0.0f;
  if constexpr (CPL == 2) {
    float2 hv = *(const float2*)(Hm + (size_t)n * F + lane * 2);
    acc0 = hv.x; acc1 = hv.y;
  } else {
    acc0 = Hm[(size_t)n * F + lane];
  }
  int j0 = start[n], j1 = start[n + 1];
  for (int cs = j0; cs < j1; cs += 64) {
    int cnt = min(64, j1 - cs);
    // phase A: lane-parallel logits
    int sj = 0;
    float e = -1e30f;
    if (lane < cnt) {
      sj = ssrc[cs + lane];
      e = lrelu(S[sj] + dn, NEG_ATT);
    }
    float cm = e;
    for (int off = 32; off; off >>= 1) cm = fmaxf(cm, __shfl_xor(cm, off));
    if (cm > m) {  // chunk-level rescale (wave-uniform)
      float r = __expf(m - cm);
      sum *= r; acc0 *= r;
      if constexpr (CPL == 2) acc1 *= r;
      m = cm;
    }
    float p = (lane < cnt) ? __expf(e - m) : 0.0f;
    float ps = p;
    for (int off = 32; off; off >>= 1) ps += __shfl_xor(ps, off);
    sum += ps;
    // phase B: broadcast accumulate, independent gathers pipelined by unroll
#pragma unroll 4
    for (int jj = 0; jj < cnt; ++jj) {
      int sjb = __shfl(sj, jj);
      float pb = __shfl(p, jj);
      if constexpr (CPL == 2) {
        float2 hv = *(const float2*)(Hm + (size_t)sjb * F + lane * 2);
        acc0 = fmaf(pb, hv.x, acc0);
        acc1 = fmaf(pb, hv.y, acc1);
      } else {
        acc0 = fmaf(pb, Hm[(size_t)sjb * F + lane], acc0);
      }
    }
  }
  float inv = 1.0f / sum;
  if constexpr (!POOL) {
    if constexpr (CPL == 2) {
      float v0 = lrelu(acc0 * inv + bias[lane * 2], NEG_ACT);
      float v1 = lrelu(acc1 * inv + bias[lane * 2 + 1], NEG_ACT);
      *(float2*)(out + (size_t)n * F + lane * 2) = make_float2(v0, v1);
    } else {
      out[(size_t)n * F + lane] = lrelu(acc0 * inv + bias[lane], NEG_ACT);
    }
  } else {
    float v0 = acc0 * inv + bias[lane];
    atomicAdd(&pool[(size_t)batch[n] * F + lane], v0);
  }
}

// ---------------- mean-pool divide ----------------
__global__ void pool_div_kernel(const float* __restrict__ pool, const int* __restrict__ gcount,
                                float* __restrict__ out, int total, int O) {
  int i = blockIdx.x * blockDim.x + threadIdx.x;
  if (i < total) {
    int g = i / O;
    out[i] = pool[i] / fmaxf((float)gcount[g], 1.0f);
  }
}

extern "C" void kernel_launch(void* const* d_in, const int* in_sizes, int n_in,
                              void* d_out, int out_size, void* d_ws, size_t ws_size,
                              hipStream_t stream) {
  const float* x      = (const float*)d_in[0];
  const int*   ei     = (const int*)d_in[1];
  const int*   batch  = (const int*)d_in[2];
  const float* W1     = (const float*)d_in[4];
  const float* a_src1 = (const float*)d_in[5];
  const float* a_dst1 = (const float*)d_in[6];
  const float* b1     = (const float*)d_in[7];
  const float* W2     = (const float*)d_in[8];
  const float* a_src2 = (const float*)d_in[9];
  const float* a_dst2 = (const float*)d_in[10];
  const float* b2     = (const float*)d_in[11];
  float* out = (float*)d_out;

  const int D = 128, H = 128, O = 64;
  int N = in_sizes[0] / D;       // 50000
  int E = in_sizes[1] / 2;       // 800000
  int G = out_size / O;          // 256
  const int* src = ei;
  const int* dst = ei + E;

  // ---- workspace carve (aligned to 256B) ----
  char* w = (char*)d_ws;
  auto alloc = [&](size_t bytes) -> char* {
    char* p = w;
    w += (bytes + 255) & ~(size_t)255;
    return p;
  };
  float* h1     = (float*)alloc((size_t)N * H * 4);  // reused as h2 after layer-1 agg
  float* act1   = (float*)alloc((size_t)N * H * 4);
  int*   ssrc   = (int*)alloc((size_t)E * 4);
  int*   start  = (int*)alloc((size_t)(N + 1) * 4);  // counts -> exclusive prefix
  int*   cursor = (int*)alloc((size_t)N * 4);
  int*   parts  = (int*)alloc(4096 * 4);
  float* s1     = (float*)alloc((size_t)N * 4);
  float* d1     = (float*)alloc((size_t)N * 4);
  float* s2     = (float*)alloc((size_t)N * 4);
  float* d2     = (float*)alloc((size_t)N * 4);
  float* pool   = (float*)alloc((size_t)G * O * 4);
  int*   gcount = (int*)alloc((size_t)G * 4);
  float* h2 = h1;  // alias: h1 dead after layer-1 aggregation

  // ---- zero the accumulated buffers (ws is NOT re-poisoned between replays) ----
  hipMemsetAsync(start, 0, (size_t)(N + 1) * 4, stream);
  hipMemsetAsync(gcount, 0, (size_t)G * 4, stream);
  hipMemsetAsync(pool, 0, (size_t)G * O * 4, stream);

  // ---- counting sort of edges by dst (shared by both layers) ----
  hist_kernel<<<(E + 255) / 256, 256, 0, stream>>>(dst, start, E);
  hist_kernel<<<(N + 255) / 256, 256, 0, stream>>>(batch, gcount, N);
  int nb = (N + 255) / 256;
  scan_block_kernel<<<nb, 256, 0, stream>>>(start, parts, N);
  scan_partials_kernel<<<1, 256, 0, stream>>>(parts, nb);
  scan_finalize_kernel<<<nb, 256, 0, stream>>>(start, cursor, parts, N, E);
  scatter_kernel<<<(E + 255) / 256, 256, 0, stream>>>(src, dst, cursor, ssrc, E);

  // ---- layer 1 ----
  gemm_sd_kernel<128, 128><<<(N + 63) / 64, 256, 0, stream>>>(x, W1, a_src1, a_dst1, h1, s1, d1, N);
  agg_kernel<128, false><<<(N + 3) / 4, 256, 0, stream>>>(h1, s1, d1, start, ssrc, b1, act1,
                                                          nullptr, nullptr, N);
  // ---- layer 2 ----
  gemm_sd_kernel<128, 64><<<(N + 63) / 64, 256, 0, stream>>>(act1, W2, a_src2, a_dst2, h2, s2, d2, N);
  agg_kernel<64, true><<<(N + 3) / 4, 256, 0, stream>>>(h2, s2, d2, start, ssrc, b2, nullptr,
                                                        batch, pool, N);
  // ---- mean pool ----
  pool_div_kernel<<<(G * O + 255) / 256, 256, 0, stream>>>(pool, gcount, out, G * O, O);
}

// Round 3
// 316.935 us; speedup vs baseline: 1.7026x; 1.2714x over previous
//
#include <hip/hip_runtime.h>

#define NEG_ATT 0.2f   // GATConv attention leaky_relu slope
#define NEG_ACT 0.01f  // inter-layer leaky_relu slope

__device__ __forceinline__ float lrelu(float x, float sl) { return x > 0.0f ? x : x * sl; }

// ---------------- histogram (edge dst counts) ----------------
__global__ void hist_kernel(const int* __restrict__ idx, int* __restrict__ count, int n) {
  int i = blockIdx.x * blockDim.x + threadIdx.x;
  if (i < n) atomicAdd(&count[idx[i]], 1);
}

// ---------------- exclusive scan (3-phase, n <= 256*256) ----------------
__global__ void scan_block_kernel(int* __restrict__ data, int* __restrict__ partials, int n) {
  __shared__ int tmp[256];
  int gid = blockIdx.x * 256 + threadIdx.x;
  int v = (gid < n) ? data[gid] : 0;
  tmp[threadIdx.x] = v;
  __syncthreads();
  for (int off = 1; off < 256; off <<= 1) {
    int t = (threadIdx.x >= (unsigned)off) ? tmp[threadIdx.x - off] : 0;
    __syncthreads();
    tmp[threadIdx.x] += t;
    __syncthreads();
  }
  if (gid < n) data[gid] = tmp[threadIdx.x] - v;  // block-local exclusive
  if (threadIdx.x == 255) partials[blockIdx.x] = tmp[255];
}

__global__ void scan_partials_kernel(int* __restrict__ partials, int nb) {
  __shared__ int tmp[256];
  int v = (threadIdx.x < (unsigned)nb) ? partials[threadIdx.x] : 0;
  tmp[threadIdx.x] = v;
  __syncthreads();
  for (int off = 1; off < 256; off <<= 1) {
    int t = (threadIdx.x >= (unsigned)off) ? tmp[threadIdx.x - off] : 0;
    __syncthreads();
    tmp[threadIdx.x] += t;
    __syncthreads();
  }
  if (threadIdx.x < (unsigned)nb) partials[threadIdx.x] = tmp[threadIdx.x] - v;
}

__global__ void scan_finalize_kernel(int* __restrict__ start, int* __restrict__ cursor,
                                     const int* __restrict__ partials, int n, int total) {
  int gid = blockIdx.x * 256 + threadIdx.x;
  if (gid < n) {
    int v = start[gid] + partials[gid >> 8];
    start[gid] = v;
    cursor[gid] = v;
  }
  if (gid == 0) start[n] = total;
}

// ---------------- counting-sort scatter: edges grouped by dst ----------------
__global__ void scatter_kernel(const int* __restrict__ src, const int* __restrict__ dst,
                               int* __restrict__ cursor, int* __restrict__ ssrc, int E) {
  int i = blockIdx.x * blockDim.x + threadIdx.x;
  if (i < E) {
    int p = atomicAdd(&cursor[dst[i]], 1);
    ssrc[p] = src[i];
  }
}

// ---------------- GEMM  h = X@W  with fused s=h@a_src, d=h@a_dst ----------------
// One wave per 16 node rows (2 groups of 8, register-blocked); W staged in LDS.
template <int DIN, int FOUT>
__global__ __launch_bounds__(256) void gemm_sd_kernel(
    const float* __restrict__ X, const float* __restrict__ W,
    const float* __restrict__ asrc, const float* __restrict__ adst,
    float* __restrict__ Ho, float* __restrict__ So, float* __restrict__ Do, int N) {
  constexpr int CPL = FOUT / 64;  // cols per lane (2 or 1)
  __shared__ float Wl[DIN * FOUT];
  __shared__ float xr[4][8][DIN];  // per-wave x-row stage (16 KB)
  int tid = threadIdx.x;
  for (int i = tid; i < DIN * FOUT; i += 256) Wl[i] = W[i];
  __syncthreads();
  int wave = tid >> 6, lane = tid & 63;
  float a0 = asrc[lane * CPL], b0 = adst[lane * CPL];
  float a1 = 0.0f, b1v = 0.0f;
  if constexpr (CPL == 2) { a1 = asrc[lane * 2 + 1]; b1v = adst[lane * 2 + 1]; }
  int base = blockIdx.x * 64 + wave * 16;
  for (int g = 0; g < 2; ++g) {
    int nb = base + g * 8;
    if (nb >= N) break;  // wave-uniform
#pragma unroll
    for (int r = 0; r < 8; ++r) {
      int n = nb + r;
      float2 xv = make_float2(0.0f, 0.0f);
      if (n < N) xv = *(const float2*)(X + (size_t)n * DIN + lane * 2);
      *(float2*)&xr[wave][r][lane * 2] = xv;
    }
    float2 acc[8];
#pragma unroll
    for (int r = 0; r < 8; ++r) acc[r] = make_float2(0.0f, 0.0f);
    for (int k = 0; k < DIN; k += 4) {
      float4 xv[8];
#pragma unroll
      for (int r = 0; r < 8; ++r) xv[r] = *(const float4*)&xr[wave][r][k];  // b128 broadcast
#pragma unroll
      for (int kk = 0; kk < 4; ++kk) {
        if constexpr (CPL == 2) {
          float2 wv = *(const float2*)&Wl[(k + kk) * FOUT + lane * 2];
#pragma unroll
          for (int r = 0; r < 8; ++r) {
            float xs = (&xv[r].x)[kk];
            acc[r].x = fmaf(xs, wv.x, acc[r].x);
            acc[r].y = fmaf(xs, wv.y, acc[r].y);
          }
        } else {
          float wv = Wl[(k + kk) * FOUT + lane];
#pragma unroll
          for (int r = 0; r < 8; ++r) acc[r].x = fmaf((&xv[r].x)[kk], wv, acc[r].x);
        }
      }
    }
#pragma unroll
    for (int r = 0; r < 8; ++r) {
      int n = nb + r;
      if (n >= N) break;  // wave-uniform
      float acc0 = acc[r].x, acc1 = acc[r].y;
      if constexpr (CPL == 2)
        *(float2*)(Ho + (size_t)n * FOUT + lane * 2) = make_float2(acc0, acc1);
      else
        Ho[(size_t)n * FOUT + lane] = acc0;
      float ps = acc0 * a0, pd = acc0 * b0;
      if constexpr (CPL == 2) { ps = fmaf(acc1, a1, ps); pd = fmaf(acc1, b1v, pd); }
      for (int off = 32; off; off >>= 1) {
        ps += __shfl_xor(ps, off);
        pd += __shfl_xor(pd, off);
      }
      if (lane == 0) { So[n] = ps; Do[n] = pd; }
    }
  }
}

// ---------------- per-dst-node attention aggregation ----------------
// GL = F/4 lanes per node-group (float4 per lane); 64/GL nodes per wave.
// Phase A: lane-parallel logits + group shfl reduce. (sj,p) stashed in LDS.
// Phase B: broadcast ds_read of stash + 8-deep pipelined row gathers.
template <int F, bool ACT>
__global__ __launch_bounds__(256) void agg_kernel(
    const float* __restrict__ Hm, const float* __restrict__ S, const float* __restrict__ Dv,
    const int* __restrict__ start, const int* __restrict__ ssrc,
    const float* __restrict__ bias, float* __restrict__ out, int N) {
  constexpr int GL = F / 4;      // lanes per group (32 or 16)
  constexpr int GPW = 64 / GL;   // groups per wave (2 or 4)
  constexpr int GPB = 4 * GPW;   // nodes per block
  __shared__ int2 stash[GPB][GL];
  int tid = threadIdx.x;
  int wave = tid >> 6, lane = tid & 63;
  int grp = lane / GL, gl = lane % GL;
  int gid = wave * GPW + grp;
  int n = blockIdx.x * GPB + gid;
  if (n >= N) return;  // per-group exec mask; stash is group-private, no barrier used
  float dn = Dv[n];
  float m = lrelu(S[n] + dn, NEG_ATT);  // self-loop logit
  float sum = 1.0f;                     // exp(self - m) = 1
  float4 acc = *(const float4*)(Hm + (size_t)n * F + gl * 4);
  int j0 = start[n], j1 = start[n + 1];
  for (int cs = j0; cs < j1; cs += GL) {
    int cnt = min(GL, j1 - cs);
    // phase A: lane-parallel logits
    int sj = 0;
    float e = -1e30f;
    if (gl < cnt) {
      sj = ssrc[cs + gl];
      e = lrelu(S[sj] + dn, NEG_ATT);
    }
    float cm = e;
#pragma unroll
    for (int off = GL / 2; off; off >>= 1) cm = fmaxf(cm, __shfl_xor(cm, off));
    if (cm > m) {  // group-uniform rescale
      float r = __expf(m - cm);
      sum *= r;
      acc.x *= r; acc.y *= r; acc.z *= r; acc.w *= r;
      m = cm;
    }
    float p = (gl < cnt) ? __expf(e - m) : 0.0f;
    float ps = p;
#pragma unroll
    for (int off = GL / 2; off; off >>= 1) ps += __shfl_xor(ps, off);
    sum += ps;
    stash[gid][gl] = make_int2(sj, __float_as_int(p));
    // phase B: full batches of 8, no conditionals
    int full = cnt & ~7;
    for (int bb = 0; bb < full; bb += 8) {
      int2 sp[8];
#pragma unroll
      for (int t = 0; t < 8; ++t) sp[t] = stash[gid][bb + t];
      float4 hv[8];
#pragma unroll
      for (int t = 0; t < 8; ++t) hv[t] = *(const float4*)(Hm + (size_t)sp[t].x * F + gl * 4);
#pragma unroll
      for (int t = 0; t < 8; ++t) {
        float pb = __int_as_float(sp[t].y);
        acc.x = fmaf(pb, hv[t].x, acc.x);
        acc.y = fmaf(pb, hv[t].y, acc.y);
        acc.z = fmaf(pb, hv[t].z, acc.z);
        acc.w = fmaf(pb, hv[t].w, acc.w);
      }
    }
    // remainder (<8)
    int rem = cnt - full;
    if (rem) {
      int2 sp[8];
      float4 hv[8];
#pragma unroll
      for (int t = 0; t < 8; ++t)
        if (t < rem) sp[t] = stash[gid][full + t];
#pragma unroll
      for (int t = 0; t < 8; ++t)
        if (t < rem) hv[t] = *(const float4*)(Hm + (size_t)sp[t].x * F + gl * 4);
#pragma unroll
      for (int t = 0; t < 8; ++t)
        if (t < rem) {
          float pb = __int_as_float(sp[t].y);
          acc.x = fmaf(pb, hv[t].x, acc.x);
          acc.y = fmaf(pb, hv[t].y, acc.y);
          acc.z = fmaf(pb, hv[t].z, acc.z);
          acc.w = fmaf(pb, hv[t].w, acc.w);
        }
    }
  }
  float inv = 1.0f / sum;
  float4 bv = *(const float4*)(bias + gl * 4);
  float4 o;
  if constexpr (ACT) {
    o.x = lrelu(acc.x * inv + bv.x, NEG_ACT);
    o.y = lrelu(acc.y * inv + bv.y, NEG_ACT);
    o.z = lrelu(acc.z * inv + bv.z, NEG_ACT);
    o.w = lrelu(acc.w * inv + bv.w, NEG_ACT);
  } else {
    o.x = acc.x * inv + bv.x;
    o.y = acc.y * inv + bv.y;
    o.z = acc.z * inv + bv.z;
    o.w = acc.w * inv + bv.w;
  }
  *(float4*)(out + (size_t)n * F + gl * 4) = o;
}

// ---------------- mean pool: one block per graph, batch sorted ----------------
__global__ __launch_bounds__(256) void pool_kernel(const float* __restrict__ emb,
                                                   const int* __restrict__ batch,
                                                   float* __restrict__ out, int N) {
  int g = blockIdx.x;
  auto lower = [&](int key) {
    int lo = 0, hi = N;
    while (lo < hi) {
      int mid = (lo + hi) >> 1;
      if (batch[mid] < key) lo = mid + 1; else hi = mid;
    }
    return lo;
  };
  int lo = lower(g), hi = lower(g + 1);
  int c = threadIdx.x & 63, r = threadIdx.x >> 6;
  float s = 0.0f;
  for (int n = lo + r; n < hi; n += 4) s += emb[(size_t)n * 64 + c];
  __shared__ float red[4][64];
  red[r][c] = s;
  __syncthreads();
  if (r == 0) {
    float tot = red[0][c] + red[1][c] + red[2][c] + red[3][c];
    out[g * 64 + c] = tot / fmaxf((float)(hi - lo), 1.0f);
  }
}

extern "C" void kernel_launch(void* const* d_in, const int* in_sizes, int n_in,
                              void* d_out, int out_size, void* d_ws, size_t ws_size,
                              hipStream_t stream) {
  const float* x      = (const float*)d_in[0];
  const int*   ei     = (const int*)d_in[1];
  const int*   batch  = (const int*)d_in[2];
  const float* W1     = (const float*)d_in[4];
  const float* a_src1 = (const float*)d_in[5];
  const float* a_dst1 = (const float*)d_in[6];
  const float* b1     = (const float*)d_in[7];
  const float* W2     = (const float*)d_in[8];
  const float* a_src2 = (const float*)d_in[9];
  const float* a_dst2 = (const float*)d_in[10];
  const float* b2     = (const float*)d_in[11];
  float* out = (float*)d_out;

  const int D = 128, H = 128, O = 64;
  int N = in_sizes[0] / D;       // 50000
  int E = in_sizes[1] / 2;       // 800000
  int G = out_size / O;          // 256
  const int* src = ei;
  const int* dst = ei + E;

  // ---- workspace carve (aligned to 256B) ----
  char* w = (char*)d_ws;
  auto alloc = [&](size_t bytes) -> char* {
    char* p = w;
    w += (bytes + 255) & ~(size_t)255;
    return p;
  };
  float* h1     = (float*)alloc((size_t)N * H * 4);  // reused as h2 after layer-1 agg
  float* act1   = (float*)alloc((size_t)N * H * 4);
  float* emb    = (float*)alloc((size_t)N * O * 4);
  int*   ssrc   = (int*)alloc((size_t)E * 4);
  int*   start  = (int*)alloc((size_t)(N + 1) * 4);  // counts -> exclusive prefix
  int*   cursor = (int*)alloc((size_t)N * 4);
  int*   parts  = (int*)alloc(4096 * 4);
  float* s1     = (float*)alloc((size_t)N * 4);
  float* d1     = (float*)alloc((size_t)N * 4);
  float* s2     = (float*)alloc((size_t)N * 4);
  float* d2     = (float*)alloc((size_t)N * 4);
  float* h2 = h1;  // alias: h1 dead after layer-1 aggregation

  // ---- zero count buffer (ws is NOT re-poisoned between replays) ----
  hipMemsetAsync(start, 0, (size_t)(N + 1) * 4, stream);

  // ---- counting sort of edges by dst (shared by both layers) ----
  hist_kernel<<<(E + 255) / 256, 256, 0, stream>>>(dst, start, E);
  int nb = (N + 255) / 256;
  scan_block_kernel<<<nb, 256, 0, stream>>>(start, parts, N);
  scan_partials_kernel<<<1, 256, 0, stream>>>(parts, nb);
  scan_finalize_kernel<<<nb, 256, 0, stream>>>(start, cursor, parts, N, E);
  scatter_kernel<<<(E + 255) / 256, 256, 0, stream>>>(src, dst, cursor, ssrc, E);

  // ---- layer 1 ----
  gemm_sd_kernel<128, 128><<<(N + 63) / 64, 256, 0, stream>>>(x, W1, a_src1, a_dst1, h1, s1, d1, N);
  agg_kernel<128, true><<<(N + 7) / 8, 256, 0, stream>>>(h1, s1, d1, start, ssrc, b1, act1, N);
  // ---- layer 2 ----
  gemm_sd_kernel<128, 64><<<(N + 63) / 64, 256, 0, stream>>>(act1, W2, a_src2, a_dst2, h2, s2, d2, N);
  agg_kernel<64, false><<<(N + 15) / 16, 256, 0, stream>>>(h2, s2, d2, start, ssrc, b2, emb, N);
  // ---- mean pool (no atomics; batch is sorted) ----
  pool_kernel<<<G, 256, 0, stream>>>(emb, batch, out, N);
}

// Round 4
// 242.843 us; speedup vs baseline: 2.2221x; 1.3051x over previous
//
#include <hip/hip_runtime.h>

#define NEG_ATT 0.2f   // GATConv attention leaky_relu slope
#define NEG_ACT 0.01f  // inter-layer leaky_relu slope

typedef short bf16x8 __attribute__((ext_vector_type(8)));
typedef float f32x4 __attribute__((ext_vector_type(4)));

__device__ __forceinline__ float lrelu(float x, float sl) { return x > 0.0f ? x : x * sl; }

__device__ __forceinline__ unsigned short f2bf(float f) {  // RNE fp32->bf16
  unsigned u = __float_as_uint(f);
  u = u + 0x7FFFu + ((u >> 16) & 1u);
  return (unsigned short)(u >> 16);
}
__device__ __forceinline__ float bf2f(unsigned short h) {
  return __uint_as_float(((unsigned)h) << 16);
}

// ---------------- histogram (edge dst counts) ----------------
__global__ void hist_kernel(const int* __restrict__ idx, int* __restrict__ count, int n) {
  int i = blockIdx.x * blockDim.x + threadIdx.x;
  if (i < n) atomicAdd(&count[idx[i]], 1);
}

// ---------------- exclusive scan (3-phase, n <= 256*256) ----------------
__global__ void scan_block_kernel(int* __restrict__ data, int* __restrict__ partials, int n) {
  __shared__ int tmp[256];
  int gid = blockIdx.x * 256 + threadIdx.x;
  int v = (gid < n) ? data[gid] : 0;
  tmp[threadIdx.x] = v;
  __syncthreads();
  for (int off = 1; off < 256; off <<= 1) {
    int t = (threadIdx.x >= (unsigned)off) ? tmp[threadIdx.x - off] : 0;
    __syncthreads();
    tmp[threadIdx.x] += t;
    __syncthreads();
  }
  if (gid < n) data[gid] = tmp[threadIdx.x] - v;
  if (threadIdx.x == 255) partials[blockIdx.x] = tmp[255];
}

__global__ void scan_partials_kernel(int* __restrict__ partials, int nb) {
  __shared__ int tmp[256];
  int v = (threadIdx.x < (unsigned)nb) ? partials[threadIdx.x] : 0;
  tmp[threadIdx.x] = v;
  __syncthreads();
  for (int off = 1; off < 256; off <<= 1) {
    int t = (threadIdx.x >= (unsigned)off) ? tmp[threadIdx.x - off] : 0;
    __syncthreads();
    tmp[threadIdx.x] += t;
    __syncthreads();
  }
  if (threadIdx.x < (unsigned)nb) partials[threadIdx.x] = tmp[threadIdx.x] - v;
}

__global__ void scan_finalize_kernel(int* __restrict__ start, int* __restrict__ cursor,
                                     const int* __restrict__ partials, int n, int total) {
  int gid = blockIdx.x * 256 + threadIdx.x;
  if (gid < n) {
    int v = start[gid] + partials[gid >> 8];
    start[gid] = v;
    cursor[gid] = v;
  }
  if (gid == 0) start[n] = total;
}

// ---------------- counting-sort scatter: edges grouped by dst ----------------
__global__ void scatter_kernel(const int* __restrict__ src, const int* __restrict__ dst,
                               int* __restrict__ cursor, int* __restrict__ ssrc, int E) {
  int i = blockIdx.x * blockDim.x + threadIdx.x;
  if (i < E) {
    int p = atomicAdd(&cursor[dst[i]], 1);
    ssrc[p] = src[i];
  }
}

// ---------------- W prep: fp32 -> split bf16 hi/lo, fragment-contiguous ----------
// dest: ((k>>3)*FOUT + n)*8 + (k&7); gemm reads 16B/lane at ((ks*4+b)*FOUT+col)*8.
__global__ void prep_w_kernel(const float* __restrict__ W, unsigned short* __restrict__ hi,
                              unsigned short* __restrict__ lo, int FOUT) {
  int idx = blockIdx.x * 256 + threadIdx.x;  // idx = k*FOUT + n
  if (idx >= 128 * FOUT) return;
  int k = idx / FOUT, n = idx % FOUT;
  float w = W[idx];
  unsigned short h = f2bf(w);
  unsigned short l = f2bf(w - bf2f(h));
  int dst = ((k >> 3) * FOUT + n) * 8 + (k & 7);
  hi[dst] = h;
  lo[dst] = l;
}

// ---------------- GEMM  h = X@W  via split-bf16 MFMA, fused s/d epilogue -------
// DIN=128. Block = 64 rows x FOUT cols; 4 waves, 16 rows each.
// A/B frags packed with matching (block,elem)->k bijection k = b*8 + j, so the
// MFMA contraction (elementwise over (b,j)) is layout-permutation invariant.
template <int FOUT, bool OUT_BF16>
__global__ __launch_bounds__(256) void gemm_mfma_kernel(
    const float* __restrict__ X, const unsigned short* __restrict__ Wh,
    const unsigned short* __restrict__ Wl,
    const float* __restrict__ asrc, const float* __restrict__ adst,
    void* __restrict__ Ho, float* __restrict__ So, float* __restrict__ Do, int N) {
  constexpr int NCB = FOUT / 16;
  __shared__ __align__(16) unsigned short AB[2 * 64 * 136];  // Ah | Al, +8 pad/row
  unsigned short* Ah = AB;
  unsigned short* Al = AB + 64 * 136;
  int tid = threadIdx.x;
  int rowbase = blockIdx.x * 64;
  // stage + split X tile (64 rows x 128 cols fp32 -> bf16 hi/lo in LDS)
#pragma unroll
  for (int i = 0; i < 8; ++i) {
    int idx = i * 256 + tid;  // 2048 float4 slots
    int r = idx >> 5, c4 = (idx & 31) << 2;
    float4 v = make_float4(0.f, 0.f, 0.f, 0.f);
    if (rowbase + r < N) v = *(const float4*)(X + (size_t)(rowbase + r) * 128 + c4);
    ushort4 hv, lv;
    hv.x = f2bf(v.x); lv.x = f2bf(v.x - bf2f(hv.x));
    hv.y = f2bf(v.y); lv.y = f2bf(v.y - bf2f(hv.y));
    hv.z = f2bf(v.z); lv.z = f2bf(v.z - bf2f(hv.z));
    hv.w = f2bf(v.w); lv.w = f2bf(v.w - bf2f(hv.w));
    *(ushort4*)&Ah[r * 136 + c4] = hv;
    *(ushort4*)&Al[r * 136 + c4] = lv;
  }
  __syncthreads();
  int wave = tid >> 6, lane = tid & 63;
  int n15 = lane & 15, bq = lane >> 4;
  int rw = wave * 16;
  f32x4 acc[NCB];
#pragma unroll
  for (int c = 0; c < NCB; ++c) acc[c] = (f32x4){0.f, 0.f, 0.f, 0.f};
#pragma unroll
  for (int ks = 0; ks < 4; ++ks) {
    bf16x8 ah = *(const bf16x8*)&Ah[(rw + n15) * 136 + ks * 32 + bq * 8];
    bf16x8 al = *(const bf16x8*)&Al[(rw + n15) * 136 + ks * 32 + bq * 8];
    const unsigned short* bhb = Wh + ((size_t)(ks * 4 + bq) * FOUT + n15) * 8;
    const unsigned short* blb = Wl + ((size_t)(ks * 4 + bq) * FOUT + n15) * 8;
#pragma unroll
    for (int c = 0; c < NCB; ++c) {
      bf16x8 bh = *(const bf16x8*)(bhb + c * 16 * 8);
      bf16x8 bl = *(const bf16x8*)(blb + c * 16 * 8);
      acc[c] = __builtin_amdgcn_mfma_f32_16x16x32_bf16(ah, bl, acc[c], 0, 0, 0);
      acc[c] = __builtin_amdgcn_mfma_f32_16x16x32_bf16(al, bh, acc[c], 0, 0, 0);
      acc[c] = __builtin_amdgcn_mfma_f32_16x16x32_bf16(ah, bh, acc[c], 0, 0, 0);
    }
  }
  // s/d: lane (bq,n15) holds rows rw+4bq+i, cols cb*16+n15
  float pS[4] = {0.f, 0.f, 0.f, 0.f}, pD[4] = {0.f, 0.f, 0.f, 0.f};
#pragma unroll
  for (int c = 0; c < NCB; ++c) {
    float av = asrc[c * 16 + n15], bv = adst[c * 16 + n15];
#pragma unroll
    for (int i = 0; i < 4; ++i) {
      pS[i] = fmaf(acc[c][i], av, pS[i]);
      pD[i] = fmaf(acc[c][i], bv, pD[i]);
    }
  }
#pragma unroll
  for (int off = 8; off; off >>= 1) {
#pragma unroll
    for (int i = 0; i < 4; ++i) {
      pS[i] += __shfl_xor(pS[i], off);
      pD[i] += __shfl_xor(pD[i], off);
    }
  }
  if (n15 < 4) {
    int row = rowbase + rw + 4 * bq + n15;
    if (row < N) {
      float sv = n15 == 0 ? pS[0] : n15 == 1 ? pS[1] : n15 == 2 ? pS[2] : pS[3];
      float dv = n15 == 0 ? pD[0] : n15 == 1 ? pD[1] : n15 == 2 ? pD[2] : pD[3];
      So[row] = sv;
      Do[row] = dv;
    }
  }
  __syncthreads();  // A-tile dead; reuse LDS for coalesced output transpose
  if constexpr (OUT_BF16) {
#pragma unroll
    for (int c = 0; c < NCB; ++c)
#pragma unroll
      for (int i = 0; i < 4; ++i)
        Ah[(rw + 4 * bq + i) * 136 + c * 16 + n15] = f2bf(acc[c][i]);
    __syncthreads();
    unsigned short* out = (unsigned short*)Ho;
    int r = tid >> 2, sg = tid & 3;  // 32 bf16 per thread
    if (rowbase + r < N) {
#pragma unroll
      for (int q = 0; q < 4; ++q) {
        uint4 v = *(uint4*)&Ah[r * 136 + sg * 32 + q * 8];
        *(uint4*)(out + (size_t)(rowbase + r) * 128 + sg * 32 + q * 8) = v;
      }
    }
  } else {
    float* ldsf = (float*)AB;  // [64][72] fp32, 18KB < 34.8KB
#pragma unroll
    for (int c = 0; c < NCB; ++c)
#pragma unroll
      for (int i = 0; i < 4; ++i)
        ldsf[(rw + 4 * bq + i) * 72 + c * 16 + n15] = acc[c][i];
    __syncthreads();
    float* out = (float*)Ho;
#pragma unroll
    for (int i = 0; i < 4; ++i) {
      int idx = i * 256 + tid;  // 1024 float4 = 64 rows x 16
      int r = idx >> 4, c4 = (idx & 15) << 2;
      if (rowbase + r < N)
        *(float4*)(out + (size_t)(rowbase + r) * 64 + c4) = *(float4*)&ldsf[r * 72 + c4];
    }
  }
}

// ---------------- per-dst-node attention aggregation ----------------
// GL=16 lanes per node (16B/lane: bf16x8 or float4); 4 nodes/wave, 16/block.
template <int F, bool BF16, bool ACT>
__global__ __launch_bounds__(256) void agg_kernel(
    const void* __restrict__ Hmv, const float* __restrict__ S, const float* __restrict__ Dv,
    const int* __restrict__ start, const int* __restrict__ ssrc,
    const float* __restrict__ bias, float* __restrict__ out, int N) {
  constexpr int VPL = BF16 ? 8 : 4;  // values per lane
  constexpr int GL = F / VPL;        // 16
  constexpr int GPB = 16;            // nodes per block
  __shared__ int2 stash[GPB][GL];
  int tid = threadIdx.x;
  int wave = tid >> 6, lane = tid & 63;
  int grp = lane / GL, gl = lane % GL;
  int gid = wave * (64 / GL) + grp;
  int n = blockIdx.x * GPB + gid;
  if (n >= N) return;  // group-uniform
  const unsigned short* Hb = (const unsigned short*)Hmv;
  const float* Hf = (const float*)Hmv;
  float dn = Dv[n];
  float m = lrelu(S[n] + dn, NEG_ATT);  // self-loop logit
  float sum = 1.0f;
  float acc[VPL];
  if constexpr (BF16) {
    uint4 hv = *(const uint4*)(Hb + (size_t)n * F + gl * 8);
    acc[0] = bf2f((unsigned short)(hv.x & 0xffff)); acc[1] = __uint_as_float(hv.x & 0xffff0000u);
    acc[2] = bf2f((unsigned short)(hv.y & 0xffff)); acc[3] = __uint_as_float(hv.y & 0xffff0000u);
    acc[4] = bf2f((unsigned short)(hv.z & 0xffff)); acc[5] = __uint_as_float(hv.z & 0xffff0000u);
    acc[6] = bf2f((unsigned short)(hv.w & 0xffff)); acc[7] = __uint_as_float(hv.w & 0xffff0000u);
  } else {
    float4 hv = *(const float4*)(Hf + (size_t)n * F + gl * 4);
    acc[0] = hv.x; acc[1] = hv.y; acc[2] = hv.z; acc[3] = hv.w;
  }
  int j0 = start[n], j1 = start[n + 1];
  for (int cs = j0; cs < j1; cs += GL) {
    int cnt = min(GL, j1 - cs);
    int sj = 0;
    float e = -1e30f;
    if (gl < cnt) {
      sj = ssrc[cs + gl];
      e = lrelu(S[sj] + dn, NEG_ATT);
    }
    float cm = e;
#pragma unroll
    for (int off = GL / 2; off; off >>= 1) cm = fmaxf(cm, __shfl_xor(cm, off));
    if (cm > m) {
      float r = __expf(m - cm);
      sum *= r;
#pragma unroll
      for (int v = 0; v < VPL; ++v) acc[v] *= r;
      m = cm;
    }
    float p = (gl < cnt) ? __expf(e - m) : 0.0f;
    float ps = p;
#pragma unroll
    for (int off = GL / 2; off; off >>= 1) ps += __shfl_xor(ps, off);
    sum += ps;
    stash[gid][gl] = make_int2(sj, __float_as_int(p));
    int full = cnt & ~7;
    for (int bb = 0; bb < full; bb += 8) {
      int2 sp[8];
#pragma unroll
      for (int t = 0; t < 8; ++t) sp[t] = stash[gid][bb + t];
      if constexpr (BF16) {
        uint4 hv[8];
#pragma unroll
        for (int t = 0; t < 8; ++t) hv[t] = *(const uint4*)(Hb + (size_t)sp[t].x * F + gl * 8);
#pragma unroll
        for (int t = 0; t < 8; ++t) {
          float pb = __int_as_float(sp[t].y);
          acc[0] = fmaf(pb, __uint_as_float(hv[t].x << 16), acc[0]);
          acc[1] = fmaf(pb, __uint_as_float(hv[t].x & 0xffff0000u), acc[1]);
          acc[2] = fmaf(pb, __uint_as_float(hv[t].y << 16), acc[2]);
          acc[3] = fmaf(pb, __uint_as_float(hv[t].y & 0xffff0000u), acc[3]);
          acc[4] = fmaf(pb, __uint_as_float(hv[t].z << 16), acc[4]);
          acc[5] = fmaf(pb, __uint_as_float(hv[t].z & 0xffff0000u), acc[5]);
          acc[6] = fmaf(pb, __uint_as_float(hv[t].w << 16), acc[6]);
          acc[7] = fmaf(pb, __uint_as_float(hv[t].w & 0xffff0000u), acc[7]);
        }
      } else {
        float4 hv[8];
#pragma unroll
        for (int t = 0; t < 8; ++t) hv[t] = *(const float4*)(Hf + (size_t)sp[t].x * F + gl * 4);
#pragma unroll
        for (int t = 0; t < 8; ++t) {
          float pb = __int_as_float(sp[t].y);
          acc[0] = fmaf(pb, hv[t].x, acc[0]);
          acc[1] = fmaf(pb, hv[t].y, acc[1]);
          acc[2] = fmaf(pb, hv[t].z, acc[2]);
          acc[3] = fmaf(pb, hv[t].w, acc[3]);
        }
      }
    }
    int rem = cnt - full;
    if (rem) {
      int2 sp[8];
#pragma unroll
      for (int t = 0; t < 8; ++t)
        if (t < rem) sp[t] = stash[gid][full + t];
      if constexpr (BF16) {
        uint4 hv[8];
#pragma unroll
        for (int t = 0; t < 8; ++t)
          if (t < rem) hv[t] = *(const uint4*)(Hb + (size_t)sp[t].x * F + gl * 8);
#pragma unroll
        for (int t = 0; t < 8; ++t)
          if (t < rem) {
            float pb = __int_as_float(sp[t].y);
            acc[0] = fmaf(pb, __uint_as_float(hv[t].x << 16), acc[0]);
            acc[1] = fmaf(pb, __uint_as_float(hv[t].x & 0xffff0000u), acc[1]);
            acc[2] = fmaf(pb, __uint_as_float(hv[t].y << 16), acc[2]);
            acc[3] = fmaf(pb, __uint_as_float(hv[t].y & 0xffff0000u), acc[3]);
            acc[4] = fmaf(pb, __uint_as_float(hv[t].z << 16), acc[4]);
            acc[5] = fmaf(pb, __uint_as_float(hv[t].z & 0xffff0000u), acc[5]);
            acc[6] = fmaf(pb, __uint_as_float(hv[t].w << 16), acc[6]);
            acc[7] = fmaf(pb, __uint_as_float(hv[t].w & 0xffff0000u), acc[7]);
          }
      } else {
        float4 hv[8];
#pragma unroll
        for (int t = 0; t < 8; ++t)
          if (t < rem) hv[t] = *(const float4*)(Hf + (size_t)sp[t].x * F + gl * 4);
#pragma unroll
        for (int t = 0; t < 8; ++t)
          if (t < rem) {
            float pb = __int_as_float(sp[t].y);
            acc[0] = fmaf(pb, hv[t].x, acc[0]);
            acc[1] = fmaf(pb, hv[t].y, acc[1]);
            acc[2] = fmaf(pb, hv[t].z, acc[2]);
            acc[3] = fmaf(pb, hv[t].w, acc[3]);
          }
      }
    }
  }
  float inv = 1.0f / sum;
#pragma unroll
  for (int v = 0; v < VPL; ++v) {
    float o = acc[v] * inv + bias[gl * VPL + v];
    if constexpr (ACT) o = lrelu(o, NEG_ACT);
    out[(size_t)n * F + gl * VPL + v] = o;
  }
}

// ---------------- mean pool: one block per graph, batch sorted ----------------
__global__ __launch_bounds__(256) void pool_kernel(const float* __restrict__ emb,
                                                   const int* __restrict__ batch,
                                                   float* __restrict__ out, int N) {
  int g = blockIdx.x;
  auto lower = [&](int key) {
    int lo = 0, hi = N;
    while (lo < hi) {
      int mid = (lo + hi) >> 1;
      if (batch[mid] < key) lo = mid + 1; else hi = mid;
    }
    return lo;
  };
  int lo = lower(g), hi = lower(g + 1);
  int c = threadIdx.x & 63, r = threadIdx.x >> 6;
  float s = 0.0f;
  for (int n = lo + r; n < hi; n += 4) s += emb[(size_t)n * 64 + c];
  __shared__ float red[4][64];
  red[r][c] = s;
  __syncthreads();
  if (r == 0) {
    float tot = red[0][c] + red[1][c] + red[2][c] + red[3][c];
    out[g * 64 + c] = tot / fmaxf((float)(hi - lo), 1.0f);
  }
}

extern "C" void kernel_launch(void* const* d_in, const int* in_sizes, int n_in,
                              void* d_out, int out_size, void* d_ws, size_t ws_size,
                              hipStream_t stream) {
  const float* x      = (const float*)d_in[0];
  const int*   ei     = (const int*)d_in[1];
  const int*   batch  = (const int*)d_in[2];
  const float* W1     = (const float*)d_in[4];
  const float* a_src1 = (const float*)d_in[5];
  const float* a_dst1 = (const float*)d_in[6];
  const float* b1     = (const float*)d_in[7];
  const float* W2     = (const float*)d_in[8];
  const float* a_src2 = (const float*)d_in[9];
  const float* a_dst2 = (const float*)d_in[10];
  const float* b2     = (const float*)d_in[11];
  float* out = (float*)d_out;

  const int D = 128, H = 128, O = 64;
  int N = in_sizes[0] / D;  // 50000
  int E = in_sizes[1] / 2;  // 800000
  int G = out_size / O;     // 256
  const int* src = ei;
  const int* dst = ei + E;

  // ---- workspace carve (256B aligned) ----
  char* w = (char*)d_ws;
  auto alloc = [&](size_t bytes) -> char* {
    char* p = w;
    w += (bytes + 255) & ~(size_t)255;
    return p;
  };
  unsigned short* h1b  = (unsigned short*)alloc((size_t)N * H * 2);  // bf16 h1
  float* act1  = (float*)alloc((size_t)N * H * 4);
  float* h2    = (float*)alloc((size_t)N * O * 4);
  float* emb   = (float*)alloc((size_t)N * O * 4);
  int*   ssrc  = (int*)alloc((size_t)E * 4);
  int*   start = (int*)alloc((size_t)(N + 1) * 4);
  int*   cursor= (int*)alloc((size_t)N * 4);
  int*   parts = (int*)alloc(4096 * 4);
  float* s1    = (float*)alloc((size_t)N * 4);
  float* d1    = (float*)alloc((size_t)N * 4);
  float* s2    = (float*)alloc((size_t)N * 4);
  float* d2    = (float*)alloc((size_t)N * 4);
  unsigned short* w1h = (unsigned short*)alloc((size_t)D * H * 2);
  unsigned short* w1l = (unsigned short*)alloc((size_t)D * H * 2);
  unsigned short* w2h = (unsigned short*)alloc((size_t)H * O * 2);
  unsigned short* w2l = (unsigned short*)alloc((size_t)H * O * 2);

  hipMemsetAsync(start, 0, (size_t)(N + 1) * 4, stream);

  // ---- counting sort of edges by dst ----
  hist_kernel<<<(E + 255) / 256, 256, 0, stream>>>(dst, start, E);
  int nb = (N + 255) / 256;
  scan_block_kernel<<<nb, 256, 0, stream>>>(start, parts, N);
  scan_partials_kernel<<<1, 256, 0, stream>>>(parts, nb);
  scan_finalize_kernel<<<nb, 256, 0, stream>>>(start, cursor, parts, N, E);
  scatter_kernel<<<(E + 255) / 256, 256, 0, stream>>>(src, dst, cursor, ssrc, E);

  // ---- W prep (split bf16, fragment-packed) ----
  prep_w_kernel<<<(128 * H + 255) / 256, 256, 0, stream>>>(W1, w1h, w1l, H);
  prep_w_kernel<<<(128 * O + 255) / 256, 256, 0, stream>>>(W2, w2h, w2l, O);

  int gb = (N + 63) / 64;
  // ---- layer 1 ----
  gemm_mfma_kernel<128, true><<<gb, 256, 0, stream>>>(x, w1h, w1l, a_src1, a_dst1,
                                                      (void*)h1b, s1, d1, N);
  agg_kernel<128, true, true><<<(N + 15) / 16, 256, 0, stream>>>(h1b, s1, d1, start, ssrc,
                                                                 b1, act1, N);
  // ---- layer 2 ----
  gemm_mfma_kernel<64, false><<<gb, 256, 0, stream>>>(act1, w2h, w2l, a_src2, a_dst2,
                                                      (void*)h2, s2, d2, N);
  agg_kernel<64, false, false><<<(N + 15) / 16, 256, 0, stream>>>(h2, s2, d2, start, ssrc,
                                                                  b2, emb, N);
  // ---- mean pool ----
  pool_kernel<<<G, 256, 0, stream>>>(emb, batch, out, N);
}

// Round 5
// 199.557 us; speedup vs baseline: 2.7041x; 1.2169x over previous
//
#include <hip/hip_runtime.h>

#define NEG_ATT 0.2f   // GATConv attention leaky_relu slope
#define NEG_ACT 0.01f  // inter-layer leaky_relu slope

typedef short bf16x8 __attribute__((ext_vector_type(8)));
typedef float f32x4 __attribute__((ext_vector_type(4)));

__device__ __forceinline__ float lrelu(float x, float sl) { return x > 0.0f ? x : x * sl; }

__device__ __forceinline__ unsigned short f2bf(float f) {  // RNE fp32->bf16
  unsigned u = __float_as_uint(f);
  u = u + 0x7FFFu + ((u >> 16) & 1u);
  return (unsigned short)(u >> 16);
}
__device__ __forceinline__ float bf2f(unsigned short h) {
  return __uint_as_float(((unsigned)h) << 16);
}

// ---------------- histogram (edge dst counts) ----------------
__global__ void hist_kernel(const int* __restrict__ idx, int* __restrict__ count, int n) {
  int i = blockIdx.x * blockDim.x + threadIdx.x;
  if (i < n) atomicAdd(&count[idx[i]], 1);
}

// ---------------- exclusive scan (3-phase, n <= 256*256) ----------------
__global__ void scan_block_kernel(int* __restrict__ data, int* __restrict__ partials, int n) {
  __shared__ int tmp[256];
  int gid = blockIdx.x * 256 + threadIdx.x;
  int v = (gid < n) ? data[gid] : 0;
  tmp[threadIdx.x] = v;
  __syncthreads();
  for (int off = 1; off < 256; off <<= 1) {
    int t = (threadIdx.x >= (unsigned)off) ? tmp[threadIdx.x - off] : 0;
    __syncthreads();
    tmp[threadIdx.x] += t;
    __syncthreads();
  }
  if (gid < n) data[gid] = tmp[threadIdx.x] - v;
  if (threadIdx.x == 255) partials[blockIdx.x] = tmp[255];
}

__global__ void scan_partials_kernel(int* __restrict__ partials, int nb) {
  __shared__ int tmp[256];
  int v = (threadIdx.x < (unsigned)nb) ? partials[threadIdx.x] : 0;
  tmp[threadIdx.x] = v;
  __syncthreads();
  for (int off = 1; off < 256; off <<= 1) {
    int t = (threadIdx.x >= (unsigned)off) ? tmp[threadIdx.x - off] : 0;
    __syncthreads();
    tmp[threadIdx.x] += t;
    __syncthreads();
  }
  if (threadIdx.x < (unsigned)nb) partials[threadIdx.x] = tmp[threadIdx.x] - v;
}

// finalize scan; also init per-bucket cursors bcur[b] = start[b*128]
__global__ void scan_finalize_kernel(int* __restrict__ start, int* __restrict__ bcur,
                                     const int* __restrict__ partials, int n, int total) {
  int gid = blockIdx.x * 256 + threadIdx.x;
  if (gid < n) {
    int v = start[gid] + partials[gid >> 8];
    start[gid] = v;
    if ((gid & 127) == 0) bcur[gid >> 7] = v;
  }
  if (gid == 0) start[n] = total;
}

// ---------------- pass A: bin edges into 128-node buckets (uint2 pairs) -------
// Per-block LDS histogram -> one global atomic per (block,bucket) reserves a
// contiguous run -> runs written by a single block, temporally local => L2
// merges lines (kills the 16x write amplification of direct scatter).
#define BIN_CHUNK 4096
__global__ __launch_bounds__(256) void binA_kernel(const int* __restrict__ src,
                                                   const int* __restrict__ dst,
                                                   int* __restrict__ bcur,
                                                   uint2* __restrict__ pairs, int E, int NB) {
  __shared__ int hist[512];  // NB <= 512 (N <= 65536)
  __shared__ int cur[512];
  int tid = threadIdx.x;
  for (int t = tid; t < NB; t += 256) hist[t] = 0;
  __syncthreads();
  int base = blockIdx.x * BIN_CHUNK;
  int s[16], d[16];
#pragma unroll
  for (int i = 0; i < 16; ++i) {
    int idx = base + i * 256 + tid;
    s[i] = 0; d[i] = -1;
    if (idx < E) {
      s[i] = src[idx];
      d[i] = dst[idx];
      atomicAdd(&hist[d[i] >> 7], 1);
    }
  }
  __syncthreads();
  for (int t = tid; t < NB; t += 256) cur[t] = atomicAdd(&bcur[t], hist[t]);
  __syncthreads();
#pragma unroll
  for (int i = 0; i < 16; ++i) {
    if (d[i] >= 0) {
      int pos = atomicAdd(&cur[d[i] >> 7], 1);
      pairs[pos] = make_uint2((unsigned)s[i], (unsigned)d[i]);
    }
  }
}

// ---------------- pass B: in-LDS counting sort within each bucket -------------
// Bucket b covers nodes [b*128, b*128+128); its ssrc segment is exactly
// [start[b*128], start[b*128+nmax]) -> coalesced read + coalesced write.
#define BUCKET_CAP 3072
__global__ __launch_bounds__(256) void binB_kernel(const uint2* __restrict__ pairs,
                                                   const int* __restrict__ start,
                                                   int* __restrict__ ssrc, int N) {
  __shared__ int soff[129];
  __shared__ int lcur[128];
  __shared__ uint2 lp[BUCKET_CAP];
  __shared__ int lsorted[BUCKET_CAP];
  int b = blockIdx.x, tid = threadIdx.x;
  int dstbase = b << 7;
  int nmax = min(128, N - dstbase);
  if (tid <= nmax) soff[tid] = start[dstbase + tid];
  if (tid < 128) lcur[tid] = 0;
  __syncthreads();
  int sbase = soff[0];
  int cnt = soff[nmax] - sbase;
  if (cnt <= BUCKET_CAP) {
    for (int i = tid; i < cnt; i += 256) lp[i] = pairs[sbase + i];
    __syncthreads();
    for (int i = tid; i < cnt; i += 256) {
      int ld = (int)lp[i].y - dstbase;
      int r = atomicAdd(&lcur[ld], 1);
      lsorted[soff[ld] - sbase + r] = (int)lp[i].x;
    }
    __syncthreads();
    for (int i = tid; i < cnt; i += 256) ssrc[sbase + i] = lsorted[i];
  } else {  // statistical-impossibility fallback (mean 2046, cap 3072)
    for (int i = tid; i < cnt; i += 256) {
      uint2 e = pairs[sbase + i];
      int ld = (int)e.y - dstbase;
      int r = atomicAdd(&lcur[ld], 1);
      ssrc[soff[ld] + r] = (int)e.x;
    }
  }
}

// ---------------- W prep: fp32 -> split bf16 hi/lo, fragment-contiguous ----------
__global__ void prep_w_kernel(const float* __restrict__ W, unsigned short* __restrict__ hi,
                              unsigned short* __restrict__ lo, int FOUT) {
  int idx = blockIdx.x * 256 + threadIdx.x;  // idx = k*FOUT + n
  if (idx >= 128 * FOUT) return;
  int k = idx / FOUT, n = idx % FOUT;
  float w = W[idx];
  unsigned short h = f2bf(w);
  unsigned short l = f2bf(w - bf2f(h));
  int dst = ((k >> 3) * FOUT + n) * 8 + (k & 7);
  hi[dst] = h;
  lo[dst] = l;
}

// ---------------- GEMM  h = X@W  via split-bf16 MFMA, fused s/d epilogue -------
template <int FOUT, bool OUT_BF16>
__global__ __launch_bounds__(256) void gemm_mfma_kernel(
    const float* __restrict__ X, const unsigned short* __restrict__ Wh,
    const unsigned short* __restrict__ Wl,
    const float* __restrict__ asrc, const float* __restrict__ adst,
    void* __restrict__ Ho, float* __restrict__ So, float* __restrict__ Do, int N) {
  constexpr int NCB = FOUT / 16;
  __shared__ __align__(16) unsigned short AB[2 * 64 * 136];  // Ah | Al, +8 pad/row
  unsigned short* Ah = AB;
  unsigned short* Al = AB + 64 * 136;
  int tid = threadIdx.x;
  int rowbase = blockIdx.x * 64;
#pragma unroll
  for (int i = 0; i < 8; ++i) {
    int idx = i * 256 + tid;
    int r = idx >> 5, c4 = (idx & 31) << 2;
    float4 v = make_float4(0.f, 0.f, 0.f, 0.f);
    if (rowbase + r < N) v = *(const float4*)(X + (size_t)(rowbase + r) * 128 + c4);
    ushort4 hv, lv;
    hv.x = f2bf(v.x); lv.x = f2bf(v.x - bf2f(hv.x));
    hv.y = f2bf(v.y); lv.y = f2bf(v.y - bf2f(hv.y));
    hv.z = f2bf(v.z); lv.z = f2bf(v.z - bf2f(hv.z));
    hv.w = f2bf(v.w); lv.w = f2bf(v.w - bf2f(hv.w));
    *(ushort4*)&Ah[r * 136 + c4] = hv;
    *(ushort4*)&Al[r * 136 + c4] = lv;
  }
  __syncthreads();
  int wave = tid >> 6, lane = tid & 63;
  int n15 = lane & 15, bq = lane >> 4;
  int rw = wave * 16;
  f32x4 acc[NCB];
#pragma unroll
  for (int c = 0; c < NCB; ++c) acc[c] = (f32x4){0.f, 0.f, 0.f, 0.f};
#pragma unroll
  for (int ks = 0; ks < 4; ++ks) {
    bf16x8 ah = *(const bf16x8*)&Ah[(rw + n15) * 136 + ks * 32 + bq * 8];
    bf16x8 al = *(const bf16x8*)&Al[(rw + n15) * 136 + ks * 32 + bq * 8];
    const unsigned short* bhb = Wh + ((size_t)(ks * 4 + bq) * FOUT + n15) * 8;
    const unsigned short* blb = Wl + ((size_t)(ks * 4 + bq) * FOUT + n15) * 8;
#pragma unroll
    for (int c = 0; c < NCB; ++c) {
      bf16x8 bh = *(const bf16x8*)(bhb + c * 16 * 8);
      bf16x8 bl = *(const bf16x8*)(blb + c * 16 * 8);
      acc[c] = __builtin_amdgcn_mfma_f32_16x16x32_bf16(ah, bl, acc[c], 0, 0, 0);
      acc[c] = __builtin_amdgcn_mfma_f32_16x16x32_bf16(al, bh, acc[c], 0, 0, 0);
      acc[c] = __builtin_amdgcn_mfma_f32_16x16x32_bf16(ah, bh, acc[c], 0, 0, 0);
    }
  }
  float pS[4] = {0.f, 0.f, 0.f, 0.f}, pD[4] = {0.f, 0.f, 0.f, 0.f};
#pragma unroll
  for (int c = 0; c < NCB; ++c) {
    float av = asrc[c * 16 + n15], bv = adst[c * 16 + n15];
#pragma unroll
    for (int i = 0; i < 4; ++i) {
      pS[i] = fmaf(acc[c][i], av, pS[i]);
      pD[i] = fmaf(acc[c][i], bv, pD[i]);
    }
  }
#pragma unroll
  for (int off = 8; off; off >>= 1) {
#pragma unroll
    for (int i = 0; i < 4; ++i) {
      pS[i] += __shfl_xor(pS[i], off);
      pD[i] += __shfl_xor(pD[i], off);
    }
  }
  if (n15 < 4) {
    int row = rowbase + rw + 4 * bq + n15;
    if (row < N) {
      float sv = n15 == 0 ? pS[0] : n15 == 1 ? pS[1] : n15 == 2 ? pS[2] : pS[3];
      float dv = n15 == 0 ? pD[0] : n15 == 1 ? pD[1] : n15 == 2 ? pD[2] : pD[3];
      So[row] = sv;
      Do[row] = dv;
    }
  }
  __syncthreads();  // A-tile dead; reuse LDS for coalesced output transpose
  if constexpr (OUT_BF16) {
#pragma unroll
    for (int c = 0; c < NCB; ++c)
#pragma unroll
      for (int i = 0; i < 4; ++i)
        Ah[(rw + 4 * bq + i) * 136 + c * 16 + n15] = f2bf(acc[c][i]);
    __syncthreads();
    unsigned short* outp = (unsigned short*)Ho;
    constexpr int UPT = FOUT / 32;  // uint4s per thread
    int r = tid >> 2, sg = tid & 3;
    if (rowbase + r < N) {
#pragma unroll
      for (int q = 0; q < UPT; ++q) {
        uint4 v = *(uint4*)&Ah[r * 136 + (sg * UPT + q) * 8];
        *(uint4*)(outp + (size_t)(rowbase + r) * FOUT + (sg * UPT + q) * 8) = v;
      }
    }
  } else {
    float* ldsf = (float*)AB;
#pragma unroll
    for (int c = 0; c < NCB; ++c)
#pragma unroll
      for (int i = 0; i < 4; ++i)
        ldsf[(rw + 4 * bq + i) * 72 + c * 16 + n15] = acc[c][i];
    __syncthreads();
    float* outp = (float*)Ho;
#pragma unroll
    for (int i = 0; i < FOUT / 64; ++i) {
      int idx = i * 256 + tid;
      int r = idx / (FOUT / 4), c4 = (idx % (FOUT / 4)) << 2;
      if (rowbase + r < N)
        *(float4*)(outp + (size_t)(rowbase + r) * FOUT + c4) = *(float4*)&ldsf[r * 72 + c4];
    }
  }
}

// ---------------- per-dst-node attention aggregation ----------------
// GL lanes per node (16B/lane); 64/GL nodes per wave.
template <int F, bool BF16, bool ACT>
__global__ __launch_bounds__(256) void agg_kernel(
    const void* __restrict__ Hmv, const float* __restrict__ S, const float* __restrict__ Dv,
    const int* __restrict__ start, const int* __restrict__ ssrc,
    const float* __restrict__ bias, float* __restrict__ out, int N) {
  constexpr int VPL = BF16 ? 8 : 4;   // values per lane
  constexpr int GL = F / VPL;         // lanes per group
  constexpr int GPW = 64 / GL;        // groups per wave
  constexpr int GPB = 4 * GPW;        // nodes per block
  __shared__ int2 stash[GPB][GL];
  int tid = threadIdx.x;
  int wave = tid >> 6, lane = tid & 63;
  int grp = lane / GL, gl = lane % GL;
  int gid = wave * GPW + grp;
  int n = blockIdx.x * GPB + gid;
  if (n >= N) return;  // group-uniform
  const unsigned short* Hb = (const unsigned short*)Hmv;
  const float* Hf = (const float*)Hmv;
  float dn = Dv[n];
  float m = lrelu(S[n] + dn, NEG_ATT);  // self-loop logit
  float sum = 1.0f;
  float acc[VPL];
  if constexpr (BF16) {
    uint4 hv = *(const uint4*)(Hb + (size_t)n * F + gl * 8);
    acc[0] = bf2f((unsigned short)(hv.x & 0xffff)); acc[1] = __uint_as_float(hv.x & 0xffff0000u);
    acc[2] = bf2f((unsigned short)(hv.y & 0xffff)); acc[3] = __uint_as_float(hv.y & 0xffff0000u);
    acc[4] = bf2f((unsigned short)(hv.z & 0xffff)); acc[5] = __uint_as_float(hv.z & 0xffff0000u);
    acc[6] = bf2f((unsigned short)(hv.w & 0xffff)); acc[7] = __uint_as_float(hv.w & 0xffff0000u);
  } else {
    float4 hv = *(const float4*)(Hf + (size_t)n * F + gl * 4);
    acc[0] = hv.x; acc[1] = hv.y; acc[2] = hv.z; acc[3] = hv.w;
  }
  int j0 = start[n], j1 = start[n + 1];
  for (int cs = j0; cs < j1; cs += GL) {
    int cnt = min(GL, j1 - cs);
    int sj = 0;
    float e = -1e30f;
    if (gl < cnt) {
      sj = ssrc[cs + gl];
      e = lrelu(S[sj] + dn, NEG_ATT);
    }
    float cm = e;
#pragma unroll
    for (int off = GL / 2; off; off >>= 1) cm = fmaxf(cm, __shfl_xor(cm, off));
    if (cm > m) {
      float r = __expf(m - cm);
      sum *= r;
#pragma unroll
      for (int v = 0; v < VPL; ++v) acc[v] *= r;
      m = cm;
    }
    float p = (gl < cnt) ? __expf(e - m) : 0.0f;
    float ps = p;
#pragma unroll
    for (int off = GL / 2; off; off >>= 1) ps += __shfl_xor(ps, off);
    sum += ps;
    stash[gid][gl] = make_int2(sj, __float_as_int(p));
    int full = cnt & ~7;
    for (int bb = 0; bb < full; bb += 8) {
      int2 sp[8];
#pragma unroll
      for (int t = 0; t < 8; ++t) sp[t] = stash[gid][bb + t];
      if constexpr (BF16) {
        uint4 hv[8];
#pragma unroll
        for (int t = 0; t < 8; ++t) hv[t] = *(const uint4*)(Hb + (size_t)sp[t].x * F + gl * 8);
#pragma unroll
        for (int t = 0; t < 8; ++t) {
          float pb = __int_as_float(sp[t].y);
          acc[0] = fmaf(pb, __uint_as_float(hv[t].x << 16), acc[0]);
          acc[1] = fmaf(pb, __uint_as_float(hv[t].x & 0xffff0000u), acc[1]);
          acc[2] = fmaf(pb, __uint_as_float(hv[t].y << 16), acc[2]);
          acc[3] = fmaf(pb, __uint_as_float(hv[t].y & 0xffff0000u), acc[3]);
          acc[4] = fmaf(pb, __uint_as_float(hv[t].z << 16), acc[4]);
          acc[5] = fmaf(pb, __uint_as_float(hv[t].z & 0xffff0000u), acc[5]);
          acc[6] = fmaf(pb, __uint_as_float(hv[t].w << 16), acc[6]);
          acc[7] = fmaf(pb, __uint_as_float(hv[t].w & 0xffff0000u), acc[7]);
        }
      } else {
        float4 hv[8];
#pragma unroll
        for (int t = 0; t < 8; ++t) hv[t] = *(const float4*)(Hf + (size_t)sp[t].x * F + gl * 4);
#pragma unroll
        for (int t = 0; t < 8; ++t) {
          float pb = __int_as_float(sp[t].y);
          acc[0] = fmaf(pb, hv[t].x, acc[0]);
          acc[1] = fmaf(pb, hv[t].y, acc[1]);
          acc[2] = fmaf(pb, hv[t].z, acc[2]);
          acc[3] = fmaf(pb, hv[t].w, acc[3]);
        }
      }
    }
    int rem = cnt - full;
    if (rem) {
      int2 sp[8];
#pragma unroll
      for (int t = 0; t < 8; ++t)
        if (t < rem) sp[t] = stash[gid][full + t];
      if constexpr (BF16) {
        uint4 hv[8];
#pragma unroll
        for (int t = 0; t < 8; ++t)
          if (t < rem) hv[t] = *(const uint4*)(Hb + (size_t)sp[t].x * F + gl * 8);
#pragma unroll
        for (int t = 0; t < 8; ++t)
          if (t < rem) {
            float pb = __int_as_float(sp[t].y);
            acc[0] = fmaf(pb, __uint_as_float(hv[t].x << 16), acc[0]);
            acc[1] = fmaf(pb, __uint_as_float(hv[t].x & 0xffff0000u), acc[1]);
            acc[2] = fmaf(pb, __uint_as_float(hv[t].y << 16), acc[2]);
            acc[3] = fmaf(pb, __uint_as_float(hv[t].y & 0xffff0000u), acc[3]);
            acc[4] = fmaf(pb, __uint_as_float(hv[t].z << 16), acc[4]);
            acc[5] = fmaf(pb, __uint_as_float(hv[t].z & 0xffff0000u), acc[5]);
            acc[6] = fmaf(pb, __uint_as_float(hv[t].w << 16), acc[6]);
            acc[7] = fmaf(pb, __uint_as_float(hv[t].w & 0xffff0000u), acc[7]);
          }
      } else {
        float4 hv[8];
#pragma unroll
        for (int t = 0; t < 8; ++t)
          if (t < rem) hv[t] = *(const float4*)(Hf + (size_t)sp[t].x * F + gl * 4);
#pragma unroll
        for (int t = 0; t < 8; ++t)
          if (t < rem) {
            float pb = __int_as_float(sp[t].y);
            acc[0] = fmaf(pb, hv[t].x, acc[0]);
            acc[1] = fmaf(pb, hv[t].y, acc[1]);
            acc[2] = fmaf(pb, hv[t].z, acc[2]);
            acc[3] = fmaf(pb, hv[t].w, acc[3]);
          }
      }
    }
  }
  float inv = 1.0f / sum;
#pragma unroll
  for (int v = 0; v < VPL; ++v) {
    float o = acc[v] * inv + bias[gl * VPL + v];
    if constexpr (ACT) o = lrelu(o, NEG_ACT);
    out[(size_t)n * F + gl * VPL + v] = o;
  }
}

// ---------------- mean pool: one block per graph, batch sorted ----------------
__global__ __launch_bounds__(256) void pool_kernel(const float* __restrict__ emb,
                                                   const int* __restrict__ batch,
                                                   float* __restrict__ out, int N) {
  int g = blockIdx.x;
  auto lower = [&](int key) {
    int lo = 0, hi = N;
    while (lo < hi) {
      int mid = (lo + hi) >> 1;
      if (batch[mid] < key) lo = mid + 1; else hi = mid;
    }
    return lo;
  };
  int lo = lower(g), hi = lower(g + 1);
  int c = threadIdx.x & 63, r = threadIdx.x >> 6;
  float s = 0.0f;
  for (int n = lo + r; n < hi; n += 4) s += emb[(size_t)n * 64 + c];
  __shared__ float red[4][64];
  red[r][c] = s;
  __syncthreads();
  if (r == 0) {
    float tot = red[0][c] + red[1][c] + red[2][c] + red[3][c];
    out[g * 64 + c] = tot / fmaxf((float)(hi - lo), 1.0f);
  }
}

extern "C" void kernel_launch(void* const* d_in, const int* in_sizes, int n_in,
                              void* d_out, int out_size, void* d_ws, size_t ws_size,
                              hipStream_t stream) {
  const float* x      = (const float*)d_in[0];
  const int*   ei     = (const int*)d_in[1];
  const int*   batch  = (const int*)d_in[2];
  const float* W1     = (const float*)d_in[4];
  const float* a_src1 = (const float*)d_in[5];
  const float* a_dst1 = (const float*)d_in[6];
  const float* b1     = (const float*)d_in[7];
  const float* W2     = (const float*)d_in[8];
  const float* a_src2 = (const float*)d_in[9];
  const float* a_dst2 = (const float*)d_in[10];
  const float* b2     = (const float*)d_in[11];
  float* out = (float*)d_out;

  const int D = 128, H = 128, O = 64;
  int N = in_sizes[0] / D;  // 50000
  int E = in_sizes[1] / 2;  // 800000
  int G = out_size / O;     // 256
  const int* src = ei;
  const int* dst = ei + E;
  int NB = (N + 127) >> 7;  // 391 buckets

  // ---- workspace carve (256B aligned) ----
  char* w = (char*)d_ws;
  auto alloc = [&](size_t bytes) -> char* {
    char* p = w;
    w += (bytes + 255) & ~(size_t)255;
    return p;
  };
  unsigned short* h1b = (unsigned short*)alloc((size_t)N * H * 2);  // bf16 h1
  float* act1  = (float*)alloc((size_t)N * H * 4);
  unsigned short* h2b = (unsigned short*)alloc((size_t)N * O * 2);  // bf16 h2
  float* emb   = (float*)alloc((size_t)N * O * 4);
  int*   ssrc  = (int*)alloc((size_t)E * 4);
  uint2* pairs = (uint2*)alloc((size_t)E * 8);
  int*   start = (int*)alloc((size_t)(N + 1) * 4);
  int*   bcur  = (int*)alloc(512 * 4);
  int*   parts = (int*)alloc(4096 * 4);
  float* s1    = (float*)alloc((size_t)N * 4);
  float* d1    = (float*)alloc((size_t)N * 4);
  float* s2    = (float*)alloc((size_t)N * 4);
  float* d2    = (float*)alloc((size_t)N * 4);
  unsigned short* w1h = (unsigned short*)alloc((size_t)D * H * 2);
  unsigned short* w1l = (unsigned short*)alloc((size_t)D * H * 2);
  unsigned short* w2h = (unsigned short*)alloc((size_t)H * O * 2);
  unsigned short* w2l = (unsigned short*)alloc((size_t)H * O * 2);

  hipMemsetAsync(start, 0, (size_t)(N + 1) * 4, stream);

  // ---- CSR build: hist -> scan (+bucket cursor init) -> binned 2-pass sort ----
  hist_kernel<<<(E + 255) / 256, 256, 0, stream>>>(dst, start, E);
  int nb = (N + 255) / 256;
  scan_block_kernel<<<nb, 256, 0, stream>>>(start, parts, N);
  scan_partials_kernel<<<1, 256, 0, stream>>>(parts, nb);
  scan_finalize_kernel<<<nb, 256, 0, stream>>>(start, bcur, parts, N, E);
  binA_kernel<<<(E + BIN_CHUNK - 1) / BIN_CHUNK, 256, 0, stream>>>(src, dst, bcur, pairs, E, NB);
  binB_kernel<<<NB, 256, 0, stream>>>(pairs, start, ssrc, N);

  // ---- W prep (split bf16, fragment-packed) ----
  prep_w_kernel<<<(128 * H + 255) / 256, 256, 0, stream>>>(W1, w1h, w1l, H);
  prep_w_kernel<<<(128 * O + 255) / 256, 256, 0, stream>>>(W2, w2h, w2l, O);

  int gb = (N + 63) / 64;
  // ---- layer 1 ----
  gemm_mfma_kernel<128, true><<<gb, 256, 0, stream>>>(x, w1h, w1l, a_src1, a_dst1,
                                                      (void*)h1b, s1, d1, N);
  agg_kernel<128, true, true><<<(N + 15) / 16, 256, 0, stream>>>(h1b, s1, d1, start, ssrc,
                                                                 b1, act1, N);
  // ---- layer 2 ----
  gemm_mfma_kernel<64, true><<<gb, 256, 0, stream>>>(act1, w2h, w2l, a_src2, a_dst2,
                                                     (void*)h2b, s2, d2, N);
  agg_kernel<64, true, false><<<(N + 31) / 32, 256, 0, stream>>>(h2b, s2, d2, start, ssrc,
                                                                 b2, emb, N);
  // ---- mean pool ----
  pool_kernel<<<G, 256, 0, stream>>>(emb, batch, out, N);
}